// Round 2
// baseline (195.119 us; speedup 1.0000x reference)
//
#include <hip/hip_runtime.h>
#include <hip/hip_bf16.h>
#include <math.h>

// Problem constants (B,C,L,H fixed by setup_inputs)
#define NB 8
#define NC 512
#define NL 8192
#define NH 128
#define FEPS 1e-5f
#define NKEEP 358   // int(512*0.7)

typedef __attribute__((ext_vector_type(8))) short short8;
typedef __attribute__((ext_vector_type(4))) float f32x4;

__device__ __forceinline__ unsigned short f2bf(float x) {
  unsigned u = __float_as_uint(x);
  return (unsigned short)((u + 0x7fffu + ((u >> 16) & 1u)) >> 16);  // RNE
}
__device__ __forceinline__ unsigned pack2(float a, float b) {
  return (unsigned)f2bf(a) | ((unsigned)f2bf(b) << 16);
}

// ---------------- K0: convert gate weights to bf16, zero accumulators ----------------
__global__ __launch_bounds__(256) void k0_prep(
    const float* __restrict__ gw1, const float* __restrict__ gw2,
    unsigned short* __restrict__ gw1b, unsigned short* __restrict__ gw2b,
    float* __restrict__ csum, float* __restrict__ gsum) {
  int i = blockIdx.x * 256 + threadIdx.x;   // 256*256 = 65536 = H*C = C*H
  gw1b[i] = f2bf(gw1[i]);
  gw2b[i] = f2bf(gw2[i]);
  if (i < NB * NC) { csum[i] = 0.f; gsum[i] = 0.f; }
}

// ---------------- K2: gate network + fused x-stats; 8 waves/block for occupancy ----------------
// Block: batch b, 128 l-rows, 512 thr = 8 waves (wave w owns l-rows [16w,16w+16)).
// Occupancy: grid 512 = 2 blocks/CU (grid-capped) -> 16 waves/CU = 4 waves/SIMD
//   (prev 4-wave version: 2 waves/SIMD, latency-bound at 20% occupancy).
// GEMM1 (K=512, 8 chunks of BK=64): A = transposed c (fp32->bf16) in LDS, double-
//   buffered, one barrier/chunk; B-frag = contiguous 16B of gw1b row direct from L2.
// Fused x-stats: wave w also owns x row (b, lt*8+w); 4 float4 loads per K-chunk
//   interleave with GEMM1 (fills the otherwise-idle memory pipe; replaces old k1).
// GEMM2 (K=128): B double-buffered in the dead AsU space; A = H^T in registers.
__global__ __launch_bounds__(512, 4) void k2_gate(
    const float* __restrict__ cin, const float* __restrict__ x,
    const unsigned short* __restrict__ gw1b, const unsigned short* __restrict__ gw2b,
    const float* __restrict__ gb1, const float* __restrict__ gb2,
    float* __restrict__ gsum_g, float* __restrict__ csum_g,
    float* __restrict__ xsum, float* __restrict__ xsumsq) {
  __shared__ __align__(16) unsigned AsU[2 * 128 * 36];     // 36864B: GEMM1 A dbuf; GEMM2 reuses as B dbuf (2x16KB)
  __shared__ __align__(16) unsigned short Hts[8][16][136]; // per-wave H^T [l-local][h], pitch 136
  __shared__ float gsum_s[NC], csum_s[NC], gb2_s[NC];
  __shared__ float gb1_s[NH];

  const int t = threadIdx.x;
  const int lane = t & 63;
  const int w = t >> 6;                 // 0..7
  const int r = lane & 15;
  const int kg = lane >> 4;
  const int b = blockIdx.x >> 6;
  const int lt = blockIdx.x & 63;
  const int l0 = lt * 128;

  // staging roles (A): p = chpair 0..31 (16 threads each), q = quad 0..15
  const int p = t >> 4;
  const int q = t & 15;

  f32x4 acc[8];
#pragma unroll
  for (int i = 0; i < 8; ++i) acc[i] = (f32x4){0.f,0.f,0.f,0.f};

  const float* cbase = cin + (size_t)b * NC * NL + l0;
  const unsigned short* gw1r = gw1b + (size_t)r * NC + kg * 8;   // + ht*16*NC + k*64 + kk*32

  // fused x-stats: wave w owns x row (b, lt*8+w)
  const f32x4* xp4 = reinterpret_cast<const f32x4*>(x + ((size_t)b * NC + lt * 8 + w) * NL);
  float xs1 = 0.f, xs2 = 0.f;

  f32x4 va[2], vb[2];

#define LOADA(kch) { \
    _Pragma("unroll") \
    for (int pass = 0; pass < 2; ++pass) { \
      const float* cp0 = cbase + (size_t)((kch) * 64 + 2 * p) * NL + 64 * pass + 4 * q; \
      va[pass] = __builtin_nontemporal_load(reinterpret_cast<const f32x4*>(cp0)); \
      vb[pass] = __builtin_nontemporal_load(reinterpret_cast<const f32x4*>(cp0 + NL)); \
    } }

#define WRITEA(kch, bufi) { \
    unsigned* dst = AsU + (bufi) * (128 * 36); \
    float sa = 0.f, sb = 0.f; \
    _Pragma("unroll") \
    for (int pass = 0; pass < 2; ++pass) { \
      const int ll = 64 * pass + 4 * q; \
      sa += va[pass].x + va[pass].y + va[pass].z + va[pass].w; \
      sb += vb[pass].x + vb[pass].y + vb[pass].z + vb[pass].w; \
      dst[(ll + 0) * 36 + p] = pack2(va[pass].x, vb[pass].x); \
      dst[(ll + 1) * 36 + p] = pack2(va[pass].y, vb[pass].y); \
      dst[(ll + 2) * 36 + p] = pack2(va[pass].z, vb[pass].z); \
      dst[(ll + 3) * 36 + p] = pack2(va[pass].w, vb[pass].w); \
    } \
    sa += __shfl_xor(sa, 1); sa += __shfl_xor(sa, 2); \
    sa += __shfl_xor(sa, 4); sa += __shfl_xor(sa, 8); \
    sb += __shfl_xor(sb, 1); sb += __shfl_xor(sb, 2); \
    sb += __shfl_xor(sb, 4); sb += __shfl_xor(sb, 8); \
    if ((lane & 15) == 0) { \
      csum_s[(kch) * 64 + 2 * p]     = sa; \
      csum_s[(kch) * 64 + 2 * p + 1] = sb; \
    } }

#define XCHUNK(kch) { \
    _Pragma("unroll") \
    for (int j = 0; j < 4; ++j) { \
      f32x4 v = xp4[lane + 64 * (4 * (kch) + j)]; \
      xs1 += v.x + v.y + v.z + v.w; \
      xs2 += v.x * v.x + v.y * v.y + v.z * v.z + v.w * v.w; \
    } }

  // prologue: issue chunk-0 loads early, init smem, barrier, stage chunk 0
  LOADA(0)
  for (int i = t; i < NC; i += 512) { gsum_s[i] = 0.f; gb2_s[i] = gb2[i]; }
  if (t < NH) gb1_s[t] = gb1[t];
  __syncthreads();
  WRITEA(0, 0)
  __syncthreads();

  // ---------------- GEMM1 main loop: one barrier per K-chunk ----------------
  for (int k = 0; k < 8; ++k) {
    const int cur = k & 1;
    if (k < 7) LOADA(k + 1)               // in flight across the whole MFMA phase
    XCHUNK(k)                             // x-stats stream on the idle memory pipe
    const unsigned* Abuf = AsU + cur * (128 * 36);
#pragma unroll
    for (int kk = 0; kk < 2; ++kk) {
      const short8 a = *reinterpret_cast<const short8*>(&Abuf[(16 * w + r) * 36 + 16 * kk + 4 * kg]);
#pragma unroll
      for (int ht = 0; ht < 8; ++ht) {
        // B-frag straight from L2: gw1b[16*ht+r][k*64 + kk*32 + kg*8 .. +8)
        const short8 bf = *reinterpret_cast<const short8*>(
            gw1r + (size_t)(ht * 16) * NC + k * 64 + kk * 32);
        acc[ht] = __builtin_amdgcn_mfma_f32_16x16x32_bf16(a, bf, acc[ht], 0, 0, 0);
      }
    }
    if (k < 7) WRITEA(k + 1, cur ^ 1)     // vmcnt waits here, after MFMA issued
    __syncthreads();
  }

  // x-stats finalize (one row per wave, no atomics)
  for (int off = 32; off; off >>= 1) { xs1 += __shfl_down(xs1, off); xs2 += __shfl_down(xs2, off); }
  if (lane == 0) {
    xsum[b * NC + lt * 8 + w]   = xs1;
    xsumsq[b * NC + lt * 8 + w] = xs2;
  }

  // epilogue: bias+relu -> Hts (D map: col=lane&15, row=(lane>>4)*4+reg)
#pragma unroll
  for (int ht = 0; ht < 8; ++ht) {
    const float bias = gb1_s[16 * ht + r];
#pragma unroll
    for (int reg = 0; reg < 4; ++reg)
      Hts[w][4 * kg + reg][16 * ht + r] = f2bf(fmaxf(acc[ht][reg] + bias, 0.f));
  }
  // wave-local write->read: per-wave DS ordering, no barrier needed
  short8 af[4];
#pragma unroll
  for (int kk = 0; kk < 4; ++kk)
    af[kk] = *reinterpret_cast<const short8*>(&Hts[w][r][32 * kk + 8 * kg]);

  // ---------------- GEMM2: gsum[c] += sigmoid(H^T . gw2[c] + gb2), B dbuf in AsU space ----------------
  unsigned short* Bs2 = reinterpret_cast<unsigned short*>(AsU);
  const int crow = lane >> 4;    // 0..3
  const int bs2  = lane & 15;
  short8 bv[2];

#define LOADB2(ccn) { \
    _Pragma("unroll") \
    for (int j = 0; j < 2; ++j) { \
      const int cl = 8 * w + 4 * j + crow; \
      bv[j] = *reinterpret_cast<const short8*>(gw2b + (size_t)((ccn) * 64 + cl) * NH + bs2 * 8); \
    } }
#define WRITEB2(ccn) { \
    unsigned short* dstb = Bs2 + ((ccn) & 1) * 8192; \
    _Pragma("unroll") \
    for (int j = 0; j < 2; ++j) { \
      const int cl = 8 * w + 4 * j + crow; \
      *reinterpret_cast<short8*>(&dstb[cl * 128 + ((bs2 ^ (cl & 7)) * 8)]) = bv[j]; \
    } }

  LOADB2(0)
  WRITEB2(0)                      // safe: all waves past GEMM1's final barrier
  __syncthreads();
  for (int cc = 0; cc < 8; ++cc) {
    if (cc < 7) LOADB2(cc + 1)
    const unsigned short* Bbuf = Bs2 + (cc & 1) * 8192;
#pragma unroll
    for (int ctt = 0; ctt < 4; ++ctt) {
      f32x4 z = (f32x4){0.f,0.f,0.f,0.f};
#pragma unroll
      for (int kk = 0; kk < 4; ++kk) {
        const short8 bf = *reinterpret_cast<const short8*>(
            &Bbuf[(16 * ctt + r) * 128 + (((4 * kk + kg) ^ (r & 7)) * 8)]);
        z = __builtin_amdgcn_mfma_f32_16x16x32_bf16(af[kk], bf, z, 0, 0, 0);
      }
      const float bias = gb2_s[cc * 64 + 16 * ctt + r];
      float s = 0.f;
#pragma unroll
      for (int reg = 0; reg < 4; ++reg)
        s += 1.f / (1.f + __expf(-(z[reg] + bias)));
      s += __shfl_xor(s, 16);
      s += __shfl_xor(s, 32);
      if (lane < 16) atomicAdd(&gsum_s[cc * 64 + 16 * ctt + lane], s);
    }
    if (cc < 7) WRITEB2(cc + 1)
    __syncthreads();
  }
  for (int i = t; i < NC; i += 512) {
    atomicAdd(&gsum_g[b * NC + i], gsum_s[i]);
    atomicAdd(&csum_g[b * NC + i], csum_s[i]);
  }
}

// ---------------- K3: finalize stats + affine MLP -> per-(b,c) y = A*x + D ----------------
__global__ __launch_bounds__(256) void k3_final(
    const float* __restrict__ xsum, const float* __restrict__ xsumsq,
    const float* __restrict__ csum, const float* __restrict__ gsum,
    const float* __restrict__ mw1, const float* __restrict__ mb1,
    const float* __restrict__ mw2, const float* __restrict__ mb2,
    float* __restrict__ a_arr, float* __restrict__ d_arr) {
  __shared__ __align__(16) float cp[NC];
  __shared__ __align__(16) float hm[NH];
  __shared__ float gbv[2 * NC];
  __shared__ double red[8];
  __shared__ float mu_l_s, sig_l_s;
  const int b = blockIdx.x, t = threadIdx.x;

  double s1 = 0.0, s2 = 0.0;
  for (int c = t; c < NC; c += 256) { s1 += (double)xsum[b * NC + c]; s2 += (double)xsumsq[b * NC + c]; }
  for (int off = 32; off; off >>= 1) { s1 += __shfl_down(s1, off); s2 += __shfl_down(s2, off); }
  if ((t & 63) == 0) { red[(t >> 6) * 2] = s1; red[(t >> 6) * 2 + 1] = s2; }
  for (int c = t; c < NC; c += 256) cp[c] = csum[b * NC + c] * (1.f / NL);
  __syncthreads();
  if (t == 0) {
    double S1 = red[0] + red[2] + red[4] + red[6];
    double S2 = red[1] + red[3] + red[5] + red[7];
    double n = (double)NC * NL;
    double mu = S1 / n;
    double var = S2 / n - mu * mu;
    mu_l_s = (float)mu;
    sig_l_s = (float)sqrt(var + (double)FEPS);
  }
  __syncthreads();
  if (t < NH) {
    const float4* row = reinterpret_cast<const float4*>(mw1 + (size_t)t * NC);
    const float4* cpv = reinterpret_cast<const float4*>(cp);
    float acc = mb1[t];
    for (int i = 0; i < NC / 4; ++i) {
      float4 wv = row[i], xv = cpv[i];
      acc += wv.x * xv.x + wv.y * xv.y + wv.z * xv.z + wv.w * xv.w;
    }
    hm[t] = fmaxf(acc, 0.f);
  }
  __syncthreads();
  for (int o = t; o < 2 * NC; o += 256) {
    const float4* row = reinterpret_cast<const float4*>(mw2 + (size_t)o * NH);
    const float4* hv = reinterpret_cast<const float4*>(hm);
    float acc = mb2[o];
    for (int i = 0; i < NH / 4; ++i) {
      float4 wv = row[i], xv = hv[i];
      acc += wv.x * xv.x + wv.y * xv.y + wv.z * xv.z + wv.w * xv.w;
    }
    gbv[o] = acc;
  }
  __syncthreads();
  const float mu_l = mu_l_s, sig_l = sig_l_s;
  for (int c = t; c < NC; c += 256) {
    float gm = gsum[b * NC + c] * (1.f / NL);
    double mu_c = (double)xsum[b * NC + c] / NL;
    double var_c = (double)xsumsq[b * NC + c] / NL - mu_c * mu_c;
    float sig_c = (float)sqrt(var_c + (double)FEPS);
    float mu = gm * (float)mu_c + (1.f - gm) * mu_l;
    float sg = gm * sig_c + (1.f - gm) * sig_l;
    float gamma = gbv[c], beta = gbv[NC + c];
    float A = (1.f + gamma) / sg;
    a_arr[b * NC + c] = A;
    d_arr[b * NC + c] = beta - A * mu;
  }
}

// ---------------- K4: y = A*x + D (x from L3 if retained), nt stores, imp = sum |y| ----------------
__global__ __launch_bounds__(256) void k4_y(
    const float* __restrict__ x, const float* __restrict__ a_arr,
    const float* __restrict__ d_arr, float* __restrict__ out, float* __restrict__ imp) {
  const int bc = blockIdx.x, t = threadIdx.x;
  const float A = a_arr[bc], D = d_arr[bc];
  const f32x4* xp = reinterpret_cast<const f32x4*>(x + (size_t)bc * NL);
  f32x4* op = reinterpret_cast<f32x4*>(out + (size_t)bc * NL);
  float s = 0.f;
#pragma unroll
  for (int i = 0; i < 8; ++i) {
    f32x4 v = __builtin_nontemporal_load(xp + i * 256 + t);   // last use of x
    f32x4 y;
    y.x = fmaf(A, v.x, D); y.y = fmaf(A, v.y, D);
    y.z = fmaf(A, v.z, D); y.w = fmaf(A, v.w, D);
    s += fabsf(y.x) + fabsf(y.y) + fabsf(y.z) + fabsf(y.w);
    __builtin_nontemporal_store(y, op + i * 256 + t);         // out never re-read
  }
  for (int off = 32; off; off >>= 1) s += __shfl_down(s, off);
  __shared__ float rs[4];
  if ((t & 63) == 0) rs[t >> 6] = s;
  __syncthreads();
  if (t == 0) imp[bc] = rs[0] + rs[1] + rs[2] + rs[3];
}

// ---------------- K5: fused top-k rank (jax.lax.top_k tie semantics) + zero dropped rows ----------------
__global__ __launch_bounds__(256) void k5_apply(
    const float* __restrict__ imp, float* __restrict__ out) {
  const int bc = blockIdx.x;
  const int b = bc >> 9;            // NC = 512
  const int c = bc & (NC - 1);
  const int t = threadIdx.x;
  const float* row = imp + b * NC;
  const float mine = row[c];
  int cnt = 0;
#pragma unroll
  for (int jj = 0; jj < 2; ++jj) {
    const int j = jj * 256 + t;
    const float o = row[j];
    cnt += (o > mine) || (o == mine && j < c);
  }
  for (int off = 32; off; off >>= 1) cnt += __shfl_down(cnt, off);
  __shared__ int rs[4];
  if ((t & 63) == 0) rs[t >> 6] = cnt;
  __syncthreads();
  const int rank = rs[0] + rs[1] + rs[2] + rs[3];   // block-uniform
  if (rank < NKEEP) return;
  f32x4* op = reinterpret_cast<f32x4*>(out + (size_t)bc * NL);
  const f32x4 z = (f32x4){0.f, 0.f, 0.f, 0.f};
#pragma unroll
  for (int i = 0; i < 8; ++i) __builtin_nontemporal_store(z, op + i * 256 + t);
}

extern "C" void kernel_launch(void* const* d_in, const int* in_sizes, int n_in,
                              void* d_out, int out_size, void* d_ws, size_t ws_size,
                              hipStream_t stream) {
  const float* x   = (const float*)d_in[0];
  const float* c   = (const float*)d_in[1];
  const float* gw1 = (const float*)d_in[2];
  const float* gb1 = (const float*)d_in[3];
  const float* gw2 = (const float*)d_in[4];
  const float* gb2 = (const float*)d_in[5];
  const float* mw1 = (const float*)d_in[6];
  const float* mb1 = (const float*)d_in[7];
  const float* mw2 = (const float*)d_in[8];
  const float* mb2 = (const float*)d_in[9];
  float* out = (float*)d_out;
  char* ws = (char*)d_ws;

  unsigned short* gw1b = (unsigned short*)(ws);             // 131072 B
  unsigned short* gw2b = (unsigned short*)(ws + 131072);    // 131072 B
  float* xsum   = (float*)(ws + 262144);
  float* xsumsq = (float*)(ws + 278528);
  float* csum   = (float*)(ws + 294912);
  float* gsum   = (float*)(ws + 311296);
  float* a_arr  = (float*)(ws + 327680);
  float* d_arr  = (float*)(ws + 344064);
  float* imp    = (float*)(ws + 360448);

  k0_prep<<<256, 256, 0, stream>>>(gw1, gw2, gw1b, gw2b, csum, gsum);
  k2_gate<<<NB * (NL / 128), 512, 0, stream>>>(c, x, gw1b, gw2b, gb1, gb2, gsum, csum, xsum, xsumsq);
  k3_final<<<NB, 256, 0, stream>>>(xsum, xsumsq, csum, gsum, mw1, mb1, mw2, mb2, a_arr, d_arr);
  k4_y<<<NB * NC, 256, 0, stream>>>(x, a_arr, d_arr, out, imp);
  k5_apply<<<NB * NC, 256, 0, stream>>>(imp, out);
}